// Round 10
// baseline (178.372 us; speedup 1.0000x reference)
//
#include <hip/hip_runtime.h>

#define HIDDEN 128
#define LDSW 136            // halves; 272 B row stride, conflict-free b128 (0 conflicts measured)
#define BSHIFT 5            // dst bucket = dst >> 5 : 32 nodes = 8 KB of zh -> L1-resident
#define NBMAX 3136          // >= 3125 buckets, padded
#define CAP 448             // slots/bucket: mean 320, sigma ~18 -> +7 sigma; 448 = 64*7
#define OVF_MAX 16384

typedef _Float16 f16;
typedef f16 f16x2 __attribute__((ext_vector_type(2)));
typedef f16 f16x8 __attribute__((ext_vector_type(8)));
typedef float f32x16 __attribute__((ext_vector_type(16)));
typedef unsigned long long ull;

static __device__ __forceinline__ float fdot2(f16x2 a, f16x2 b, float c) {
    return __builtin_amdgcn_fdot2(a, b, c, false);   // v_dot2_f32_f16
}

// wsh_t[n][k] = Wsym[k][n] (fp16, B-operand layout); init cursor[b]=b*CAP, ovf_cnt=0
__global__ __launch_bounds__(256) void prep_w(const float* __restrict__ w,
                                              f16* __restrict__ wsh_t,
                                              int* __restrict__ cursor,
                                              int* __restrict__ ovf_cnt,
                                              int nb) {
    int idx = blockIdx.x * 256 + threadIdx.x;   // 0..16383
    if (idx < nb) cursor[idx] = idx * CAP;
    if (idx == nb) ovf_cnt[0] = 0;
    int n = idx >> 7, k = idx & 127;
    wsh_t[idx] = (f16)(w[k * HIDDEN + n] + w[n * HIDDEN + k]);
}

// Fused launch: blocks [0,ngemm) = MFMA gemm tiles; blocks [ngemm,..) = counting scatter.
__global__ __launch_bounds__(256) void gemm_scatter(const float* __restrict__ z,
                                                    const f16* __restrict__ wsh_t,
                                                    f16* __restrict__ zh,
                                                    f16* __restrict__ uh,
                                                    const int* __restrict__ eidx,
                                                    int* __restrict__ cursor,
                                                    ull* __restrict__ perm,
                                                    ull* __restrict__ ovf,
                                                    int* __restrict__ ovf_cnt,
                                                    int nrows, int E, int nb, int ngemm) {
    // overlay: gemm uses wlt (34816 B), scatter uses 3x NBMAX ints (37632 B)
    __shared__ __align__(16) char smem[3 * NBMAX * 4];
    int tid = threadIdx.x;

    if (blockIdx.x >= ngemm) {
        // ---- scatter path: perm[pos] = src | dst<<17 | e<<34 ----
        int* lh    = (int*)smem;
        int* lbase = lh + NBMAX;
        int* lrank = lbase + NBMAX;
        int base = (blockIdx.x - ngemm) * 4096;
        for (int i = tid; i < nb; i += 256) { lh[i] = 0; lrank[i] = 0; }
        __syncthreads();
        int s[16], d[16], bb[16];
        #pragma unroll
        for (int i = 0; i < 16; ++i) {
            int e = base + i * 256 + tid;
            bb[i] = -1;
            if (e < E) {
                s[i] = eidx[e]; d[i] = eidx[E + e];
                bb[i] = d[i] >> BSHIFT;
                atomicAdd(&lh[bb[i]], 1);
            }
        }
        __syncthreads();
        for (int i = tid; i < nb; i += 256)
            if (lh[i]) lbase[i] = atomicAdd(&cursor[i], lh[i]);
        __syncthreads();
        #pragma unroll
        for (int i = 0; i < 16; ++i) {
            if (bb[i] >= 0) {
                int e = base + i * 256 + tid;
                int r = atomicAdd(&lrank[bb[i]], 1);
                long pos = (long)lbase[bb[i]] + r;
                ull v = (ull)s[i] | ((ull)d[i] << 17) | ((ull)e << 34);
                if (pos < (long)(bb[i] + 1) * CAP) perm[pos] = v;
                else {                                   // +7 sigma: statistically never
                    int o = atomicAdd(ovf_cnt, 1);
                    if (o < OVF_MAX) ovf[o] = v;
                }
            }
        }
        return;
    }

    // ---- gemm path (R4 body, ~17 us): uh = (f16)(z @ Wsym), zh = (f16)z fused ----
    f16* wlt = (f16*)smem;
    {   // stage W^T: 2048 16B chunks, coalesced
        const f16x8* g = (const f16x8*)wsh_t;
        #pragma unroll
        for (int it = 0; it < 8; ++it) {
            int idx = it * 256 + tid;
            int j = idx >> 4, kc = idx & 15;
            *(f16x8*)&wlt[j * LDSW + kc * 8] = g[idx];
        }
    }
    __syncthreads();

    int wave = tid >> 6, lane = tid & 63;
    int row0 = blockIdx.x * 128 + wave * 32;
    if (row0 > nrows - 32) row0 = nrows - 32;   // tail overlap: identical writes, benign

    int m = lane & 31, half = lane >> 5;        // A: row=m, k=half*8+j
    const float* zr = z  + (size_t)(row0 + m) * HIDDEN + half * 8;
    f16*        zhr = zh + (size_t)(row0 + m) * HIDDEN + half * 8;
    const f16* wbase = &wlt[m * LDSW + half * 8];

    f32x16 acc0, acc1, acc2, acc3;
    #pragma unroll
    for (int r = 0; r < 16; ++r) { acc0[r] = 0.f; acc1[r] = 0.f; acc2[r] = 0.f; acc3[r] = 0.f; }

    #pragma unroll
    for (int ks = 0; ks < 8; ++ks) {            // K = 16 per step
        float4 a0 = *(const float4*)(zr + 16 * ks);
        float4 a1 = *(const float4*)(zr + 16 * ks + 4);
        f16x8 af = {(f16)a0.x, (f16)a0.y, (f16)a0.z, (f16)a0.w,
                    (f16)a1.x, (f16)a1.y, (f16)a1.z, (f16)a1.w};
        *(f16x8*)(zhr + 16 * ks) = af;          // fused zh emit
        f16x8 b0 = *(const f16x8*)(wbase + 16 * ks);
        f16x8 b1 = *(const f16x8*)(wbase + 32 * LDSW + 16 * ks);
        f16x8 b2 = *(const f16x8*)(wbase + 64 * LDSW + 16 * ks);
        f16x8 b3 = *(const f16x8*)(wbase + 96 * LDSW + 16 * ks);
        acc0 = __builtin_amdgcn_mfma_f32_32x32x16_f16(af, b0, acc0, 0, 0, 0);
        acc1 = __builtin_amdgcn_mfma_f32_32x32x16_f16(af, b1, acc1, 0, 0, 0);
        acc2 = __builtin_amdgcn_mfma_f32_32x32x16_f16(af, b2, acc2, 0, 0, 0);
        acc3 = __builtin_amdgcn_mfma_f32_32x32x16_f16(af, b3, acc3, 0, 0, 0);
    }

    // C/D: col = m (+32/tile), row = (r&3) + 8*(r>>2) + 4*half   [m74/m101]
    f16* ur = uh + (size_t)row0 * HIDDEN;
    #pragma unroll
    for (int r = 0; r < 16; ++r) {
        int row = (r & 3) + 8 * (r >> 2) + 4 * half;
        f16* p = ur + (size_t)row * HIDDEN + m;
        p[0]  = (f16)acc0[r];
        p[32] = (f16)acc1[r];
        p[64] = (f16)acc2[r];
        p[96] = (f16)acc3[r];
    }
}

// Gathers unconditional (slack slots decode to one constant in-workspace row -> L1-hit);
// store predicated on eid < E.
static __device__ __forceinline__ void score_edge(const f16* uh, const f16* zh,
                                                  ull p, float* out, int t, int E) {
    int src = (int)(p & 0x1FFFF);
    int dst = (int)((p >> 17) & 0x1FFFF);
    int eid = (int)(p >> 34);
    const float4* a4 = (const float4*)(uh + (size_t)src * HIDDEN);
    const float4* b4 = (const float4*)(zh + (size_t)dst * HIDDEN);
    float4 av = a4[t], bv = b4[t];   // src: random (L2/L3); dst: bucket-resident (L1)
    const f16x2* ap = (const f16x2*)&av;
    const f16x2* bp = (const f16x2*)&bv;
    float s = 0.f;
    #pragma unroll
    for (int i = 0; i < 4; ++i) s = fdot2(ap[i], bp[i], s);
    #pragma unroll
    for (int off = 8; off > 0; off >>= 1) s += __shfl_down(s, off, 16);
    if (t == 0 && eid < E) out[eid] = 1.0f / (1.0f + __expf(-s));
}

// One 1024-thread block per dst bucket (64 groups x 7 slots): 32-node dst set stays in L1.
// XCD swizzle keeps each XCD on a contiguous bucket range (L2-local dst slice).
__global__ __launch_bounds__(1024) void edge_bin(const f16* __restrict__ uh,
                                                 const f16* __restrict__ zh,
                                                 const ull* __restrict__ perm,
                                                 const ull* __restrict__ ovf,
                                                 const int* __restrict__ ovf_cnt,
                                                 float* __restrict__ out,
                                                 int E, int cpb, int nb, int nmain) {
    int tid = threadIdx.x;
    int g = tid >> 4, t = tid & 15;           // 64 groups of 16 lanes
    int b = blockIdx.x;
    if (b >= nmain) {                         // overflow tail (statistically empty)
        int n = ovf_cnt[0];
        if (n > OVF_MAX) n = OVF_MAX;
        for (int i = (b - nmain) * 64 + g; i < n; i += 32 * 64)
            score_edge(uh, zh, ovf[i], out, t, E);
        return;
    }
    int B = (b & 7) * cpb + (b >> 3);         // XCD b%8 -> contiguous bucket range
    if (B >= nb) return;
    long base = (long)B * CAP;
    #pragma unroll 2
    for (int j = 0; j < CAP / 64; ++j)        // 7 slots per group, groups read coalesced
        score_edge(uh, zh, perm[base + (long)j * 64 + g], out, t, E);
}

// fallback (R5 path) if workspace too small for the binned layout
__global__ __launch_bounds__(256) void edge_score16(const f16* __restrict__ uh,
                                                    const f16* __restrict__ zh,
                                                    const int* __restrict__ eidx,
                                                    float* __restrict__ out, int E) {
    int tid = threadIdx.x;
    int g = tid >> 4, t = tid & 15;
    int e = blockIdx.x * 16 + g;
    if (e >= E) return;
    ull p = (ull)eidx[e] | ((ull)eidx[E + e] << 17) | ((ull)e << 34);
    score_edge(uh, zh, p, out, t, E);
}

extern "C" void kernel_launch(void* const* d_in, const int* in_sizes, int n_in,
                              void* d_out, int out_size, void* d_ws, size_t ws_size,
                              hipStream_t stream) {
    const float* z    = (const float*)d_in[0];
    const int*   eidx = (const int*)d_in[1];
    const float* w    = (const float*)d_in[2];
    float* out = (float*)d_out;

    int nrows = in_sizes[0] / HIDDEN;        // 100000
    int E = out_size;                         // 1000000
    int nb = ((nrows - 1) >> BSHIFT) + 1;     // 3125

    f16* wsh_t  = (f16*)d_ws;                               // 32 KB
    f16* zh     = wsh_t + HIDDEN * HIDDEN;                  // 25.6 MB
    f16* uh     = zh + (size_t)nrows * HIDDEN;              // 25.6 MB
    int* cursor = (int*)(uh + (size_t)nrows * HIDDEN);      // nb ints
    int* ovf_cnt = cursor + NBMAX;                          // 2 ints
    ull* ovf    = (ull*)(ovf_cnt + 2);                      // 128 KB
    ull* perm   = ovf + OVF_MAX;                            // nb*CAP slots (~11.2 MB)

    long nslots = (long)nb * CAP;
    size_t need = (size_t)((char*)(perm + nslots) - (char*)d_ws);
    bool binned = ws_size >= need;       // ws_size fixed per session -> same path every call

    int ngemm = (nrows + 127) / 128;     // 782
    int nscat = (E + 4095) / 4096;       // 245

    prep_w<<<64, 256, 0, stream>>>(w, wsh_t, cursor, ovf_cnt, nb);
    if (binned) {
        gemm_scatter<<<ngemm + nscat, 256, 0, stream>>>(z, wsh_t, zh, uh, eidx, cursor,
                                                        perm, ovf, ovf_cnt, nrows, E, nb, ngemm);
        int cpb = (nb + 7) / 8;           // 391
        int nmain = 8 * cpb;              // 3128
        edge_bin<<<nmain + 32, 1024, 0, stream>>>(uh, zh, perm, ovf, ovf_cnt, out,
                                                  E, cpb, nb, nmain);
    } else {
        gemm_scatter<<<ngemm, 256, 0, stream>>>(z, wsh_t, zh, uh, eidx, cursor,
                                                perm, ovf, ovf_cnt, nrows, E, nb, ngemm);
        edge_score16<<<(E + 15) / 16, 256, 0, stream>>>(uh, zh, eidx, out, E);
    }
}

// Round 11
// 171.949 us; speedup vs baseline: 1.0374x; 1.0374x over previous
//
#include <hip/hip_runtime.h>

#define HIDDEN 128
#define LDSW 136            // halves; 272 B row stride, conflict-free b128 (0 conflicts measured)
#define BSHIFT 5            // dst bucket = dst >> 5 : 32 consecutive nodes = 8 KB of zh
#define BS 32               // nodes per bucket
#define NBMAX 3136          // >= 3125 buckets, padded
#define CAP 384             // slots/bucket: mean 320, sigma ~18 -> +3.6 sigma; ovf path covers rest
#define OVF_MAX 16384

typedef _Float16 f16;
typedef f16 f16x2 __attribute__((ext_vector_type(2)));
typedef f16 f16x8 __attribute__((ext_vector_type(8)));
typedef float f32x16 __attribute__((ext_vector_type(16)));
typedef unsigned long long ull;

static __device__ __forceinline__ float fdot2(f16x2 a, f16x2 b, float c) {
    return __builtin_amdgcn_fdot2(a, b, c, false);   // v_dot2_f32_f16
}

// wsh_t[n][k] = Wsym[k][n] (fp16, B-operand layout); init cursor[b]=b*CAP, ovf_cnt=0
__global__ __launch_bounds__(256) void prep_w(const float* __restrict__ w,
                                              f16* __restrict__ wsh_t,
                                              int* __restrict__ cursor,
                                              int* __restrict__ ovf_cnt,
                                              int nb) {
    int idx = blockIdx.x * 256 + threadIdx.x;   // 0..16383
    if (idx < nb) cursor[idx] = idx * CAP;
    if (idx == nb) ovf_cnt[0] = 0;
    int n = idx >> 7, k = idx & 127;
    wsh_t[idx] = (f16)(w[k * HIDDEN + n] + w[n * HIDDEN + k]);
}

// Fused launch: blocks [0,ngemm) = MFMA gemm tiles; blocks [ngemm,..) = counting scatter.
__global__ __launch_bounds__(256) void gemm_scatter(const float* __restrict__ z,
                                                    const f16* __restrict__ wsh_t,
                                                    f16* __restrict__ zh,
                                                    f16* __restrict__ uh,
                                                    const int* __restrict__ eidx,
                                                    int* __restrict__ cursor,
                                                    ull* __restrict__ perm,
                                                    ull* __restrict__ ovf,
                                                    int* __restrict__ ovf_cnt,
                                                    int nrows, int E, int nb, int ngemm) {
    // overlay: gemm uses wlt (34816 B), scatter uses 3x NBMAX ints (37632 B)
    __shared__ __align__(16) char smem[3 * NBMAX * 4];
    int tid = threadIdx.x;

    if (blockIdx.x >= ngemm) {
        // ---- scatter path: perm[pos] = src | dst<<17 | e<<34 ----
        int* lh    = (int*)smem;
        int* lbase = lh + NBMAX;
        int* lrank = lbase + NBMAX;
        int base = (blockIdx.x - ngemm) * 4096;
        for (int i = tid; i < nb; i += 256) { lh[i] = 0; lrank[i] = 0; }
        __syncthreads();
        int s[16], d[16], bb[16];
        #pragma unroll
        for (int i = 0; i < 16; ++i) {
            int e = base + i * 256 + tid;
            bb[i] = -1;
            if (e < E) {
                s[i] = eidx[e]; d[i] = eidx[E + e];
                bb[i] = d[i] >> BSHIFT;
                atomicAdd(&lh[bb[i]], 1);
            }
        }
        __syncthreads();
        for (int i = tid; i < nb; i += 256)
            if (lh[i]) lbase[i] = atomicAdd(&cursor[i], lh[i]);
        __syncthreads();
        #pragma unroll
        for (int i = 0; i < 16; ++i) {
            if (bb[i] >= 0) {
                int e = base + i * 256 + tid;
                int r = atomicAdd(&lrank[bb[i]], 1);
                long pos = (long)lbase[bb[i]] + r;
                ull v = (ull)s[i] | ((ull)d[i] << 17) | ((ull)e << 34);
                if (pos < (long)(bb[i] + 1) * CAP) perm[pos] = v;
                else {                                   // few edges per run at most
                    int o = atomicAdd(ovf_cnt, 1);
                    if (o < OVF_MAX) ovf[o] = v;
                }
            }
        }
        return;
    }

    // ---- gemm path (R4 body, ~17 us): uh = (f16)(z @ Wsym), zh = (f16)z fused ----
    f16* wlt = (f16*)smem;
    {   // stage W^T: 2048 16B chunks, coalesced
        const f16x8* g = (const f16x8*)wsh_t;
        #pragma unroll
        for (int it = 0; it < 8; ++it) {
            int idx = it * 256 + tid;
            int j = idx >> 4, kc = idx & 15;
            *(f16x8*)&wlt[j * LDSW + kc * 8] = g[idx];
        }
    }
    __syncthreads();

    int wave = tid >> 6, lane = tid & 63;
    int row0 = blockIdx.x * 128 + wave * 32;
    if (row0 > nrows - 32) row0 = nrows - 32;   // tail overlap: identical writes, benign

    int m = lane & 31, half = lane >> 5;        // A: row=m, k=half*8+j
    const float* zr = z  + (size_t)(row0 + m) * HIDDEN + half * 8;
    f16*        zhr = zh + (size_t)(row0 + m) * HIDDEN + half * 8;
    const f16* wbase = &wlt[m * LDSW + half * 8];

    f32x16 acc0, acc1, acc2, acc3;
    #pragma unroll
    for (int r = 0; r < 16; ++r) { acc0[r] = 0.f; acc1[r] = 0.f; acc2[r] = 0.f; acc3[r] = 0.f; }

    #pragma unroll
    for (int ks = 0; ks < 8; ++ks) {            // K = 16 per step
        float4 a0 = *(const float4*)(zr + 16 * ks);
        float4 a1 = *(const float4*)(zr + 16 * ks + 4);
        f16x8 af = {(f16)a0.x, (f16)a0.y, (f16)a0.z, (f16)a0.w,
                    (f16)a1.x, (f16)a1.y, (f16)a1.z, (f16)a1.w};
        *(f16x8*)(zhr + 16 * ks) = af;          // fused zh emit
        f16x8 b0 = *(const f16x8*)(wbase + 16 * ks);
        f16x8 b1 = *(const f16x8*)(wbase + 32 * LDSW + 16 * ks);
        f16x8 b2 = *(const f16x8*)(wbase + 64 * LDSW + 16 * ks);
        f16x8 b3 = *(const f16x8*)(wbase + 96 * LDSW + 16 * ks);
        acc0 = __builtin_amdgcn_mfma_f32_32x32x16_f16(af, b0, acc0, 0, 0, 0);
        acc1 = __builtin_amdgcn_mfma_f32_32x32x16_f16(af, b1, acc1, 0, 0, 0);
        acc2 = __builtin_amdgcn_mfma_f32_32x32x16_f16(af, b2, acc2, 0, 0, 0);
        acc3 = __builtin_amdgcn_mfma_f32_32x32x16_f16(af, b3, acc3, 0, 0, 0);
    }

    // C/D: col = m (+32/tile), row = (r&3) + 8*(r>>2) + 4*half   [m74/m101]
    f16* ur = uh + (size_t)row0 * HIDDEN;
    #pragma unroll
    for (int r = 0; r < 16; ++r) {
        int row = (r & 3) + 8 * (r >> 2) + 4 * half;
        f16* p = ur + (size_t)row * HIDDEN + m;
        p[0]  = (f16)acc0[r];
        p[32] = (f16)acc1[r];
        p[64] = (f16)acc2[r];
        p[96] = (f16)acc3[r];
    }
}

// generic scorer (dst from global) — used by overflow tail + fallback path
static __device__ __forceinline__ void score_edge(const f16* uh, const f16* zh,
                                                  ull p, float* out, int t, int E) {
    int src = (int)(p & 0x1FFFF);
    int dst = (int)((p >> 17) & 0x1FFFF);
    int eid = (int)(p >> 34);
    const float4* a4 = (const float4*)(uh + (size_t)src * HIDDEN);
    const float4* b4 = (const float4*)(zh + (size_t)dst * HIDDEN);
    float4 av = a4[t], bv = b4[t];
    const f16x2* ap = (const f16x2*)&av;
    const f16x2* bp = (const f16x2*)&bv;
    float s = 0.f;
    #pragma unroll
    for (int i = 0; i < 4; ++i) s = fdot2(ap[i], bp[i], s);
    #pragma unroll
    for (int off = 8; off > 0; off >>= 1) s += __shfl_down(s, off, 16);
    if (t == 0 && eid < E) out[eid] = 1.0f / (1.0f + __expf(-s));
}

// One 256-thread block per dst bucket. The bucket's 32 dst rows (contiguous 8 KB of zh)
// are preloaded into LDS -> dst side issues ZERO per-edge L2 requests, no L1-thrash risk.
// Count read once per block (amortized); slack slots skipped by bound (no sentinel reads).
__global__ __launch_bounds__(256) void edge_bin(const f16* __restrict__ uh,
                                                const f16* __restrict__ zh,
                                                const ull* __restrict__ perm,
                                                const int* __restrict__ cursor,
                                                const ull* __restrict__ ovf,
                                                const int* __restrict__ ovf_cnt,
                                                float* __restrict__ out,
                                                int E, int cpb, int nb, int nmain) {
    int tid = threadIdx.x;
    int g = tid >> 4, t = tid & 15;           // 16 groups x 16 lanes
    int b = blockIdx.x;
    if (b >= nmain) {                         // overflow tail (few edges at most)
        int n = ovf_cnt[0];
        if (n > OVF_MAX) n = OVF_MAX;
        for (int i = (b - nmain) * 16 + g; i < n; i += 32 * 16)
            score_edge(uh, zh, ovf[i], out, t, E);
        return;
    }
    int B = (b & 7) * cpb + (b >> 3);         // XCD b%8 -> contiguous bucket range (L2-local)
    if (B >= nb) return;

    __shared__ f16 dloc[BS * HIDDEN];         // 8 KB: this bucket's dst rows
    __shared__ int cnt_s;
    {   // preload: contiguous zh region, perfectly coalesced (256 thr x 32 B)
        const float4* zsrc = (const float4*)(zh + (size_t)B * BS * HIDDEN);
        float4* dl = (float4*)dloc;
        dl[tid]       = zsrc[tid];
        dl[tid + 256] = zsrc[tid + 256];
    }
    if (tid == 0) cnt_s = cursor[B] - B * CAP;   // one load per block, off critical path
    __syncthreads();
    int cnt = cnt_s; if (cnt > CAP) cnt = CAP;

    long base = (long)B * CAP;
    for (int j = g; j < cnt; j += 16) {
        ull p = perm[base + j];               // broadcast within group
        int src = (int)(p & 0x1FFFF);
        int dl  = (int)((p >> 17) & (BS - 1));
        int eid = (int)(p >> 34);
        float4 av = ((const float4*)(uh + (size_t)src * HIDDEN))[t];   // only per-edge L2 traffic
        f16x8  bv = *(const f16x8*)&dloc[dl * HIDDEN + t * 8];         // LDS, ~free
        const f16x2* ap = (const f16x2*)&av;
        const f16x2* bp = (const f16x2*)&bv;
        float s = 0.f;
        #pragma unroll
        for (int i = 0; i < 4; ++i) s = fdot2(ap[i], bp[i], s);
        #pragma unroll
        for (int off = 8; off > 0; off >>= 1) s += __shfl_down(s, off, 16);
        if (t == 0 && eid < E) out[eid] = 1.0f / (1.0f + __expf(-s));
    }
}

// fallback (R5 path) if workspace too small for the binned layout
__global__ __launch_bounds__(256) void edge_score16(const f16* __restrict__ uh,
                                                    const f16* __restrict__ zh,
                                                    const int* __restrict__ eidx,
                                                    float* __restrict__ out, int E) {
    int tid = threadIdx.x;
    int g = tid >> 4, t = tid & 15;
    int e = blockIdx.x * 16 + g;
    if (e >= E) return;
    ull p = (ull)eidx[e] | ((ull)eidx[E + e] << 17) | ((ull)e << 34);
    score_edge(uh, zh, p, out, t, E);
}

extern "C" void kernel_launch(void* const* d_in, const int* in_sizes, int n_in,
                              void* d_out, int out_size, void* d_ws, size_t ws_size,
                              hipStream_t stream) {
    const float* z    = (const float*)d_in[0];
    const int*   eidx = (const int*)d_in[1];
    const float* w    = (const float*)d_in[2];
    float* out = (float*)d_out;

    int nrows = in_sizes[0] / HIDDEN;        // 100000
    int E = out_size;                         // 1000000
    int nb = ((nrows - 1) >> BSHIFT) + 1;     // 3125

    f16* wsh_t  = (f16*)d_ws;                               // 32 KB
    f16* zh     = wsh_t + HIDDEN * HIDDEN;                  // 25.6 MB
    f16* uh     = zh + (size_t)nrows * HIDDEN;              // 25.6 MB
    int* cursor = (int*)(uh + (size_t)nrows * HIDDEN);      // nb ints
    int* ovf_cnt = cursor + NBMAX;                          // 2 ints
    ull* ovf    = (ull*)(ovf_cnt + 2);                      // 128 KB
    ull* perm   = ovf + OVF_MAX;                            // nb*CAP slots (~9.6 MB)

    long nslots = (long)nb * CAP;
    size_t need = (size_t)((char*)(perm + nslots) - (char*)d_ws);
    bool binned = ws_size >= need;       // ws_size fixed per session -> same path every call

    int ngemm = (nrows + 127) / 128;     // 782
    int nscat = (E + 4095) / 4096;       // 245

    prep_w<<<64, 256, 0, stream>>>(w, wsh_t, cursor, ovf_cnt, nb);
    if (binned) {
        gemm_scatter<<<ngemm + nscat, 256, 0, stream>>>(z, wsh_t, zh, uh, eidx, cursor,
                                                        perm, ovf, ovf_cnt, nrows, E, nb, ngemm);
        int cpb = (nb + 7) / 8;           // 391
        int nmain = 8 * cpb;              // 3128
        edge_bin<<<nmain + 32, 256, 0, stream>>>(uh, zh, perm, cursor, ovf, ovf_cnt, out,
                                                 E, cpb, nb, nmain);
    } else {
        gemm_scatter<<<ngemm, 256, 0, stream>>>(z, wsh_t, zh, uh, eidx, cursor,
                                                perm, ovf, ovf_cnt, nrows, E, nb, ngemm);
        edge_score16<<<(E + 15) / 16, 256, 0, stream>>>(uh, zh, eidx, out, E);
    }
}